// Round 6
// baseline (180.002 us; speedup 1.0000x reference)
//
#include <hip/hip_runtime.h>
#include <hip/hip_bf16.h>

#define NN 16384
#define SIZE 256
#define DISTD 64
#define KNBR 16
#define HEADS 8
#define HIDDEN 512
#define HA 256
#define SCALE 0.17677669529663687f

typedef __bf16 bf16;
typedef bf16 bf16x2 __attribute__((ext_vector_type(2)));
typedef bf16 bf16x4 __attribute__((ext_vector_type(4)));
typedef bf16 bf16x8 __attribute__((ext_vector_type(8)));
typedef float f32x4 __attribute__((ext_vector_type(4)));

__device__ __forceinline__ void gload16(const void* g, void* l) {
    __builtin_amdgcn_global_load_lds(
        (const __attribute__((address_space(1))) unsigned int*)g,
        (__attribute__((address_space(3))) unsigned int*)l, 16, 0, 0);
}

// ---------------------------------------------------------------------------
// 2-phase double-buffered 128x128 GEMM (as round 5, verified).
// ---------------------------------------------------------------------------
template<bool BIAS, bool RELU_OUT, bool RESID, typename OutT>
__global__ __launch_bounds__(256) void gemm128(
    const bf16* __restrict__ A, const bf16* __restrict__ BT,
    const float* __restrict__ bias, const float* __restrict__ resid,
    OutT* __restrict__ C, int M, int N, int K)
{
    __shared__ alignas(16) bf16 As[2][128][32];
    __shared__ alignas(16) bf16 Bs[2][128][32];

    const int t = threadIdx.x;
    const int w = t >> 6, l = t & 63;
    const int bm = blockIdx.y * 128, bn = blockIdx.x * 128;
    const int wr = (w >> 1) * 64, wc = (w & 1) * 64;

    f32x4 acc[4][4] = {};

    const bf16* ag = A  + (size_t)(bm + (t >> 2)) * K + (t & 3) * 8;
    const bf16* bg = BT + (size_t)(bn + (t >> 2)) * K + (t & 3) * 8;

    const int nt = K >> 5;
    {
        bf16* asl = &As[0][w << 4][0];
        bf16* bsl = &Bs[0][w << 4][0];
        gload16(ag, asl);
        gload16(ag + (size_t)64 * K, (char*)asl + 4096);
        gload16(bg, bsl);
        gload16(bg + (size_t)64 * K, (char*)bsl + 4096);
    }
    __syncthreads();

    for (int tt = 0; tt < nt; ++tt) {
        const int cur = tt & 1;
        if (tt + 1 < nt) {
            const int k0 = (tt + 1) << 5;
            bf16* asl = &As[cur ^ 1][w << 4][0];
            bf16* bsl = &Bs[cur ^ 1][w << 4][0];
            gload16(ag + k0, asl);
            gload16(ag + k0 + (size_t)64 * K, (char*)asl + 4096);
            gload16(bg + k0, bsl);
            gload16(bg + k0 + (size_t)64 * K, (char*)bsl + 4096);
        }
        bf16x8 af[4], bfr[4];
        #pragma unroll
        for (int m = 0; m < 4; ++m)
            af[m] = *(const bf16x8*)&As[cur][wr + m * 16 + (l & 15)][(l >> 4) * 8];
        #pragma unroll
        for (int n2 = 0; n2 < 4; ++n2)
            bfr[n2] = *(const bf16x8*)&Bs[cur][wc + n2 * 16 + (l & 15)][(l >> 4) * 8];
        #pragma unroll
        for (int m = 0; m < 4; ++m)
            #pragma unroll
            for (int n2 = 0; n2 < 4; ++n2)
                acc[m][n2] = __builtin_amdgcn_mfma_f32_16x16x32_bf16(
                    af[m], bfr[n2], acc[m][n2], 0, 0, 0);
        __syncthreads();
    }

    #pragma unroll
    for (int m = 0; m < 4; ++m) {
        const int row = bm + wr + m * 16 + ((l >> 4) << 2);
        #pragma unroll
        for (int n2 = 0; n2 < 4; ++n2) {
            const int col = bn + wc + n2 * 16 + (l & 15);
            #pragma unroll
            for (int i = 0; i < 4; ++i) {
                float v = acc[m][n2][i];
                if (BIAS) v += bias[col];
                if (RESID) v += resid[(size_t)(row + i) * N + col];
                if (RELU_OUT) v = fmaxf(v, 0.f);
                C[(size_t)(row + i) * N + col] = (OutT)v;
            }
        }
    }
}

// ---------------------------------------------------------------------------
// Fused G1 + qcat dispatch (both K=256). grid (10,128):
//  bx<4  : H0  = relu(frbf @ W0T + b0)          (bf16, ld 512)
//  bx=4,5: qbf = fbf @ Wq_cols + bq             (bf16, ld 256, pre-scaled)
//  bx>=6 : qprojF = fbf @ Wqp_cols + bqp        (f32,  ld 512, pre-scaled)
// ---------------------------------------------------------------------------
__global__ __launch_bounds__(256) void g1qcat_kernel(
    const bf16* __restrict__ fbf, const bf16* __restrict__ frbf,
    const bf16* __restrict__ W0T, const float* __restrict__ b0,
    const bf16* __restrict__ WqcatT, const float* __restrict__ bqcat,
    bf16* __restrict__ H0, bf16* __restrict__ qbf, float* __restrict__ qprojF)
{
    __shared__ alignas(16) bf16 As[2][128][32];
    __shared__ alignas(16) bf16 Bs[2][128][32];

    const int bx = blockIdx.x, by = blockIdx.y;
    const bool isG1 = bx < 4;
    const int cx = bx - 4;
    const bf16* A  = isG1 ? frbf : fbf;
    const bf16* BT = isG1 ? (W0T + (size_t)bx * 128 * 256)
                          : (WqcatT + (size_t)cx * 128 * 256);
    const float* bias = isG1 ? (b0 + bx * 128) : (bqcat + cx * 128);
    const int K = 256;

    const int t = threadIdx.x;
    const int w = t >> 6, l = t & 63;
    const int bm = by * 128;
    const int wr = (w >> 1) * 64, wc = (w & 1) * 64;

    f32x4 acc[4][4] = {};

    const bf16* ag = A  + (size_t)(bm + (t >> 2)) * K + (t & 3) * 8;
    const bf16* bg = BT + (size_t)(t >> 2) * K + (t & 3) * 8;

    {
        bf16* asl = &As[0][w << 4][0];
        bf16* bsl = &Bs[0][w << 4][0];
        gload16(ag, asl);
        gload16(ag + (size_t)64 * K, (char*)asl + 4096);
        gload16(bg, bsl);
        gload16(bg + (size_t)64 * K, (char*)bsl + 4096);
    }
    __syncthreads();

    for (int tt = 0; tt < 8; ++tt) {
        const int cur = tt & 1;
        if (tt + 1 < 8) {
            const int k0 = (tt + 1) << 5;
            bf16* asl = &As[cur ^ 1][w << 4][0];
            bf16* bsl = &Bs[cur ^ 1][w << 4][0];
            gload16(ag + k0, asl);
            gload16(ag + k0 + (size_t)64 * K, (char*)asl + 4096);
            gload16(bg + k0, bsl);
            gload16(bg + k0 + (size_t)64 * K, (char*)bsl + 4096);
        }
        bf16x8 af[4], bfr[4];
        #pragma unroll
        for (int m = 0; m < 4; ++m)
            af[m] = *(const bf16x8*)&As[cur][wr + m * 16 + (l & 15)][(l >> 4) * 8];
        #pragma unroll
        for (int n2 = 0; n2 < 4; ++n2)
            bfr[n2] = *(const bf16x8*)&Bs[cur][wc + n2 * 16 + (l & 15)][(l >> 4) * 8];
        #pragma unroll
        for (int m = 0; m < 4; ++m)
            #pragma unroll
            for (int n2 = 0; n2 < 4; ++n2)
                acc[m][n2] = __builtin_amdgcn_mfma_f32_16x16x32_bf16(
                    af[m], bfr[n2], acc[m][n2], 0, 0, 0);
        __syncthreads();
    }

    #pragma unroll
    for (int m = 0; m < 4; ++m) {
        const int lrow = wr + m * 16 + ((l >> 4) << 2);
        #pragma unroll
        for (int n2 = 0; n2 < 4; ++n2) {
            const int lcol = wc + n2 * 16 + (l & 15);
            #pragma unroll
            for (int i = 0; i < 4; ++i) {
                float v = acc[m][n2][i] + bias[lcol];
                const size_t row = bm + lrow + i;
                if (isG1) {
                    H0[row * 512 + bx * 128 + lcol] = (bf16)fmaxf(v, 0.f);
                } else if (cx < 2) {
                    qbf[row * 256 + cx * 128 + lcol] = (bf16)v;
                } else {
                    qprojF[row * 512 + (cx - 2) * 128 + lcol] = v;
                }
            }
        }
    }
}

// ---------------------------------------------------------------------------
// Fused prep: blocks [0,4096) = features f32->bf16 (+relu copy);
//             blocks [4096,8196) = weight transposes/casts + algebra.
// WqcatT/bqcat are PRE-SCALED by 1/sqrt(32).
// ---------------------------------------------------------------------------
__global__ __launch_bounds__(256) void prep_all(
    const float* __restrict__ features,
    const float* __restrict__ W0, const float* __restrict__ W1,
    const float* __restrict__ W2, const float* __restrict__ Wq,
    const float* __restrict__ bq, const float* __restrict__ Wk,
    const float* __restrict__ Wv, const float* __restrict__ Wo,
    const float* __restrict__ bo, const float* __restrict__ bv,
    bf16* __restrict__ fbf, bf16* __restrict__ frbf,
    bf16* __restrict__ W0T, bf16* __restrict__ W1T, bf16* __restrict__ W2T,
    bf16* __restrict__ WkvT, bf16* __restrict__ WqcatT, bf16* __restrict__ WstackT,
    float* __restrict__ bqcat, float* __restrict__ biaso)
{
    if (blockIdx.x < 4096) {
        int id = blockIdx.x * 256 + threadIdx.x;
        float4 v = ((const float4*)features)[id];
        bf16x4 a, r;
        a[0] = (bf16)v.x; a[1] = (bf16)v.y; a[2] = (bf16)v.z; a[3] = (bf16)v.w;
        r[0] = (bf16)fmaxf(v.x, 0.f); r[1] = (bf16)fmaxf(v.y, 0.f);
        r[2] = (bf16)fmaxf(v.z, 0.f); r[3] = (bf16)fmaxf(v.w, 0.f);
        ((bf16x4*)fbf)[id] = a; ((bf16x4*)frbf)[id] = r;
        return;
    }
    long id = (blockIdx.x - 4096) * 256L + threadIdx.x;
    if (id < 131072) {  // W0T[n][k] = W0[k][n], 512x256
        int n = id >> 8, k = id & 255;
        W0T[id] = (bf16)W0[(long)k * 512 + n]; return;
    }
    id -= 131072;
    if (id < 262144) {  // W1T, 512x512
        int n = id >> 9, k = id & 511;
        W1T[id] = (bf16)W1[(long)k * 512 + n]; return;
    }
    id -= 262144;
    if (id < 131072) {  // W2T, 256x512
        int n = id >> 9, k = id & 511;
        W2T[id] = (bf16)W2[(long)k * 256 + n]; return;
    }
    id -= 131072;
    if (id < 131072) {  // WkvT 512x256
        int n = id >> 8, k = id & 255;
        WkvT[id] = (bf16)(n < 256 ? Wk[(long)k * 256 + n] : Wv[(long)k * 256 + (n - 256)]);
        return;
    }
    id -= 131072;
    if (id < 196608) {  // WqcatT[col][c], 768x256, scaled
        int col = id >> 8, c = id & 255;
        float s;
        if (col < 256) s = Wq[(long)c * 256 + col];
        else {
            int hd = col - 256, h = hd >> 6, d = hd & 63;
            s = 0.f;
            #pragma unroll
            for (int a = 0; a < 32; ++a)
                s += Wq[(long)c * 256 + h * 32 + a] * Wk[(long)(256 + d) * 256 + h * 32 + a];
        }
        WqcatT[id] = (bf16)(s * SCALE); return;
    }
    id -= 196608;
    if (id < 196608) {  // WstackT[col][r], 256x768
        int col = (int)(id / 768), r = (int)(id % 768);
        float s;
        if (r < 256) s = Wo[(long)r * 256 + col];
        else {
            int hd = r - 256, h = hd >> 6, d = hd & 63;
            s = 0.f;
            #pragma unroll
            for (int a = 0; a < 32; ++a)
                s += Wv[(long)(256 + d) * 256 + h * 32 + a] * Wo[(long)(h * 32 + a) * 256 + col];
        }
        WstackT[id] = (bf16)s; return;
    }
    id -= 196608;
    if (id < 768) {     // bqcat, scaled
        float s;
        if (id < 256) s = bq[id];
        else {
            int hd = (int)id - 256, h = hd >> 6, d = hd & 63;
            s = 0.f;
            #pragma unroll
            for (int a = 0; a < 32; ++a)
                s += bq[h * 32 + a] * Wk[(long)(256 + d) * 256 + h * 32 + a];
        }
        bqcat[id] = s * SCALE; return;
    }
    id -= 768;
    if (id < 256) {     // biaso = bo + bv @ Wo
        float s = bo[id];
        for (int u = 0; u < 256; ++u) s += bv[u] * Wo[(long)u * 256 + id];
        biaso[id] = s;
    }
}

// ---------------------------------------------------------------------------
// Attention: one block per node. Scores pre-scaled (fold into Wqcat).
// Phase C: waves 0-1 -> o (col pairs, bf16x2 LDS reads);
//          waves 2-3 -> wd (4-wide, float4 LDS reads).
// ---------------------------------------------------------------------------
__global__ __launch_bounds__(256) void attn_kernel(
    const bf16*  __restrict__ qbf,      // [NN, 256] bf16 (pre-scaled q)
    const float* __restrict__ qprojF,   // [NN, 512] f32  (pre-scaled qproj)
    const bf16*  __restrict__ localKV,  // [NN, 512] bf16 (K | V)
    const float* __restrict__ dist,     // [NN, 16, 64]
    const int*   __restrict__ structure,// [NN, 16]
    bf16* __restrict__ concat)          // [NN, 768]
{
    const int n = blockIdx.x;
    const int t = threadIdx.x;
    const int h = t >> 5, j = (t >> 1) & 15, part = t & 1;

    __shared__ float dist_s[16][68];   // rows 16B-aligned (68*4=272), b128-friendly
    __shared__ bf16  V_s[16][264];
    __shared__ float attn_s[8][16];
    __shared__ int   s_s[16];

    {
        const float* dp = dist + (long)n * (KNBR * DISTD);
        #pragma unroll
        for (int i = 0; i < 4; ++i) {
            int e = i * 256 + t;
            dist_s[e >> 6][e & 63] = dp[e];
        }
    }
    if (t < 16) s_s[t] = structure[(long)n * KNBR + t];
    __syncthreads();

    // V -> LDS (coalesced 16B per thread x2)
    #pragma unroll
    for (int pass = 0; pass < 2; ++pass) {
        int idx = pass * 256 + t;
        int row = idx >> 5, chunk = idx & 31;
        bf16x8 v = *(const bf16x8*)(localKV + (long)s_s[row] * 512 + 256 + chunk * 8);
        *(bf16x8*)&V_s[row][chunk * 8] = v;
    }

    // q (bf16) and qproj (f32) slices in registers
    const bf16* qq = qbf + (long)n * 256 + h * 32 + part * 16;
    bf16x8 qa = *(const bf16x8*)qq;
    bf16x8 qb = *(const bf16x8*)(qq + 8);
    const float* qpp = qprojF + (long)n * 512 + h * 64 + part * 32;
    float4 qp4[8];
    #pragma unroll
    for (int i = 0; i < 8; ++i) qp4[i] = ((const float4*)qpp)[i];

    const bf16* kp = localKV + (long)s_s[j] * 512 + h * 32 + part * 16;
    bf16x8 ka = *(const bf16x8*)kp;
    bf16x8 kb = *(const bf16x8*)(kp + 8);

    float sc = 0.f;
    #pragma unroll
    for (int i = 0; i < 8; ++i)
        sc += (float)qa[i] * (float)ka[i] + (float)qb[i] * (float)kb[i];

    const int dbase = part * 32;
    #pragma unroll
    for (int i = 0; i < 8; ++i) {
        sc += dist_s[j][dbase + 4 * i + 0] * qp4[i].x;
        sc += dist_s[j][dbase + 4 * i + 1] * qp4[i].y;
        sc += dist_s[j][dbase + 4 * i + 2] * qp4[i].z;
        sc += dist_s[j][dbase + 4 * i + 3] * qp4[i].w;
    }

    sc += __shfl_xor(sc, 1);           // combine part halves -> full (pre-scaled) score
    float m = sc;
    m = fmaxf(m, __shfl_xor(m, 2));
    m = fmaxf(m, __shfl_xor(m, 4));
    m = fmaxf(m, __shfl_xor(m, 8));
    m = fmaxf(m, __shfl_xor(m, 16));
    float e = __expf(sc - m);
    float sum = e;
    sum += __shfl_xor(sum, 2);
    sum += __shfl_xor(sum, 4);
    sum += __shfl_xor(sum, 8);
    sum += __shfl_xor(sum, 16);
    float attn = e / sum;
    if (!part) attn_s[h][j] = attn;
    __syncthreads();

    if (t < 128) {
        // o: col pair (2t, 2t+1)
        const int c0 = t * 2;
        const int hh = t >> 4;
        float a0 = 0.f, a1 = 0.f;
        #pragma unroll
        for (int j2 = 0; j2 < 16; ++j2) {
            float wgt = attn_s[hh][j2];
            bf16x2 pv = *(const bf16x2*)&V_s[j2][c0];
            a0 += wgt * (float)pv[0];
            a1 += wgt * (float)pv[1];
        }
        bf16x2 o2; o2[0] = (bf16)a0; o2[1] = (bf16)a1;
        *(bf16x2*)&concat[(long)n * 768 + c0] = o2;
    } else {
        // wd: 4 outputs (u*4 .. u*4+3)
        const int u = t - 128;
        const int base = u * 4;
        const int h3 = u >> 4, d3 = (u & 15) * 4;
        f32x4 acc4 = {};
        #pragma unroll
        for (int j2 = 0; j2 < 16; ++j2) {
            float wgt = attn_s[h3][j2];
            const f32x4 dv = *(const f32x4*)&dist_s[j2][d3];
            acc4 += wgt * dv;
        }
        bf16x4 o4;
        #pragma unroll
        for (int i = 0; i < 4; ++i) o4[i] = (bf16)acc4[i];
        *(bf16x4*)&concat[(long)n * 768 + 256 + base] = o4;
    }
}

// ---------------------------------------------------------------------------
extern "C" void kernel_launch(void* const* d_in, const int* in_sizes, int n_in,
                              void* d_out, int out_size, void* d_ws, size_t ws_size,
                              hipStream_t stream)
{
    const float* features = (const float*)d_in[0];
    const float* dist     = (const float*)d_in[1];
    const int*   structure= (const int*)d_in[2];
    const float* W0 = (const float*)d_in[3];
    const float* b0 = (const float*)d_in[4];
    const float* W1 = (const float*)d_in[5];
    const float* b1 = (const float*)d_in[6];
    const float* W2 = (const float*)d_in[7];
    const float* b2 = (const float*)d_in[8];
    const float* Wq = (const float*)d_in[9];
    const float* bq = (const float*)d_in[10];
    const float* Wk = (const float*)d_in[11];
    // d_in[12] = bk : dropped exactly (softmax-invariant per-head shift)
    const float* Wv = (const float*)d_in[13];
    const float* bv = (const float*)d_in[14];
    const float* Wo = (const float*)d_in[15];
    const float* bo = (const float*)d_in[16];
    float* out = (float*)d_out;

    const size_t MB = 1u << 20;
    char* w = (char*)d_ws;
    // live intervals (MiB):
    float* qprojF  = (float*)(w + 0 * MB);   // [0,32)   g1qcat -> attn
    bf16*  qbf     = (bf16*)(w + 32 * MB);   // [32,40)  g1qcat -> attn
    bf16*  H0      = (bf16*)(w + 40 * MB);   // [40,56)  g1qcat -> G2
    bf16*  local_b = (bf16*)(w + 40 * MB);   // [40,48)  G3 -> KV   (H0 dead)
    bf16*  concat  = (bf16*)(w + 48 * MB);   // [48,72)  attn -> final (H0/H1 dead)
    bf16*  fbf     = (bf16*)(w + 56 * MB);   // [56,64)  prep -> g1qcat
    bf16*  frbf    = (bf16*)(w + 64 * MB);   // [64,72)  prep -> g1qcat
    bf16*  H1      = (bf16*)(w + 56 * MB);   // [56,72)  G2 -> G3   (fbf/frbf dead)
    bf16*  localKV = (bf16*)(w + 72 * MB);   // [72,88)  KV -> attn
    char*  wb      = w + 88 * MB;            // weights: prep -> final
    bf16*  W0T     = (bf16*)(wb + 0);
    bf16*  W1T     = (bf16*)(wb + 262144);
    bf16*  W2T     = (bf16*)(wb + 786432);
    bf16*  WkvT    = (bf16*)(wb + 1048576);
    bf16*  WqcatT  = (bf16*)(wb + 1310720);
    bf16*  WstackT = (bf16*)(wb + 1703936);
    float* bqcat   = (float*)(wb + 2097152);
    float* biaso   = (float*)(wb + 2100224);

    dim3 blk(256);

    prep_all<<<dim3(8196), blk, 0, stream>>>(
        features, W0, W1, W2, Wq, bq, Wk, Wv, Wo, bo, bv,
        fbf, frbf, W0T, W1T, W2T, WkvT, WqcatT, WstackT, bqcat, biaso);

    // fused: H0 = relu(relu(f)@W0+b0); [qbf|qprojF] = f@Wqcat+bqcat (pre-scaled)
    g1qcat_kernel<<<dim3(10, 128), blk, 0, stream>>>(
        fbf, frbf, W0T, b0, WqcatT, bqcat, H0, qbf, qprojF);

    gemm128<true,  true,  false, bf16><<<dim3(4, 128), blk, 0, stream>>>(
        H0, W1T, b1, nullptr, H1, NN, 512, 512);
    gemm128<true,  true,  false, bf16><<<dim3(2, 128), blk, 0, stream>>>(
        H1, W2T, b2, nullptr, local_b, NN, 256, 512);

    // localKV = local @ [Wk_top | Wv_top]
    gemm128<false, false, false, bf16><<<dim3(4, 128), blk, 0, stream>>>(
        local_b, WkvT, nullptr, nullptr, localKV, NN, 512, 256);

    attn_kernel<<<dim3(NN), blk, 0, stream>>>(
        qbf, qprojF, localKV, dist, structure, concat);

    // out = concat @ [Wo ; U] + (bo + bv@Wo) + features
    gemm128<true,  false, true,  float><<<dim3(2, 128), blk, 0, stream>>>(
        concat, WstackT, biaso, features, out, NN, 256, 768);
}

// Round 7
// 178.091 us; speedup vs baseline: 1.0107x; 1.0107x over previous
//
#include <hip/hip_runtime.h>
#include <hip/hip_bf16.h>

#define NN 16384
#define SIZE 256
#define DISTD 64
#define KNBR 16
#define HEADS 8
#define HIDDEN 512
#define HA 256
#define SCALE 0.17677669529663687f

typedef __bf16 bf16;
typedef bf16 bf16x2 __attribute__((ext_vector_type(2)));
typedef bf16 bf16x4 __attribute__((ext_vector_type(4)));
typedef bf16 bf16x8 __attribute__((ext_vector_type(8)));
typedef float f32x4 __attribute__((ext_vector_type(4)));

__device__ __forceinline__ void gload16(const void* g, void* l) {
    __builtin_amdgcn_global_load_lds(
        (const __attribute__((address_space(1))) unsigned int*)g,
        (__attribute__((address_space(3))) unsigned int*)l, 16, 0, 0);
}

// ---------------------------------------------------------------------------
// 2-phase double-buffered GEMM, 128xTN tile (TN = 128 or 64).
// TN=64 doubles grid -> 2-4 blocks/CU for latency overlap on small-N shapes.
// ---------------------------------------------------------------------------
template<bool BIAS, bool RELU_OUT, bool RESID, typename OutT, int TN>
__global__ __launch_bounds__(256) void gemm128(
    const bf16* __restrict__ A, const bf16* __restrict__ BT,
    const float* __restrict__ bias, const float* __restrict__ resid,
    OutT* __restrict__ C, int M, int N, int K)
{
    constexpr int NF = TN / 32;                 // B-frags per wave (4 or 2)
    __shared__ alignas(16) bf16 As[2][128][32];
    __shared__ alignas(16) bf16 Bs[2][TN][32];

    const int t = threadIdx.x;
    const int w = t >> 6, l = t & 63;
    const int bm = blockIdx.y * 128, bn = blockIdx.x * TN;
    const int wr = (w >> 1) * 64, wc = (w & 1) * (TN / 2);

    f32x4 acc[4][NF] = {};

    const bf16* ag = A  + (size_t)(bm + (t >> 2)) * K + (t & 3) * 8;
    const bf16* bg = BT + (size_t)(bn + (t >> 2)) * K + (t & 3) * 8;

    const int nt = K >> 5;
    {
        bf16* asl = &As[0][w << 4][0];
        bf16* bsl = &Bs[0][w << 4][0];
        gload16(ag, asl);
        gload16(ag + (size_t)64 * K, (char*)asl + 4096);
        gload16(bg, bsl);
        if constexpr (TN == 128)
            gload16(bg + (size_t)64 * K, (char*)bsl + 4096);
    }
    __syncthreads();

    for (int tt = 0; tt < nt; ++tt) {
        const int cur = tt & 1;
        if (tt + 1 < nt) {
            const int k0 = (tt + 1) << 5;
            bf16* asl = &As[cur ^ 1][w << 4][0];
            bf16* bsl = &Bs[cur ^ 1][w << 4][0];
            gload16(ag + k0, asl);
            gload16(ag + k0 + (size_t)64 * K, (char*)asl + 4096);
            gload16(bg + k0, bsl);
            if constexpr (TN == 128)
                gload16(bg + k0 + (size_t)64 * K, (char*)bsl + 4096);
        }
        bf16x8 af[4], bfr[NF];
        #pragma unroll
        for (int m = 0; m < 4; ++m)
            af[m] = *(const bf16x8*)&As[cur][wr + m * 16 + (l & 15)][(l >> 4) * 8];
        #pragma unroll
        for (int n2 = 0; n2 < NF; ++n2)
            bfr[n2] = *(const bf16x8*)&Bs[cur][wc + n2 * 16 + (l & 15)][(l >> 4) * 8];
        #pragma unroll
        for (int m = 0; m < 4; ++m)
            #pragma unroll
            for (int n2 = 0; n2 < NF; ++n2)
                acc[m][n2] = __builtin_amdgcn_mfma_f32_16x16x32_bf16(
                    af[m], bfr[n2], acc[m][n2], 0, 0, 0);
        __syncthreads();
    }

    #pragma unroll
    for (int m = 0; m < 4; ++m) {
        const int row = bm + wr + m * 16 + ((l >> 4) << 2);
        #pragma unroll
        for (int n2 = 0; n2 < NF; ++n2) {
            const int col = bn + wc + n2 * 16 + (l & 15);
            #pragma unroll
            for (int i = 0; i < 4; ++i) {
                float v = acc[m][n2][i];
                if (BIAS) v += bias[col];
                if (RESID) v += resid[(size_t)(row + i) * N + col];
                if (RELU_OUT) v = fmaxf(v, 0.f);
                C[(size_t)(row + i) * N + col] = (OutT)v;
            }
        }
    }
}

// ---------------------------------------------------------------------------
// Fused G1 + qcat dispatch (both K=256). grid (10,128):
//  bx<4 : H0   = relu(frbf @ W0T + b0)            (bf16, ld 512)
//  bx>=4: qcat = fbf @ Wqcat_cols + bqcat          (bf16, ld 768, pre-scaled)
// ---------------------------------------------------------------------------
__global__ __launch_bounds__(256) void g1qcat_kernel(
    const bf16* __restrict__ fbf, const bf16* __restrict__ frbf,
    const bf16* __restrict__ W0T, const float* __restrict__ b0,
    const bf16* __restrict__ WqcatT, const float* __restrict__ bqcat,
    bf16* __restrict__ H0, bf16* __restrict__ qcat)
{
    __shared__ alignas(16) bf16 As[2][128][32];
    __shared__ alignas(16) bf16 Bs[2][128][32];

    const int bx = blockIdx.x, by = blockIdx.y;
    const bool isG1 = bx < 4;
    const int cx = bx - 4;
    const bf16* A  = isG1 ? frbf : fbf;
    const bf16* BT = isG1 ? (W0T + (size_t)bx * 128 * 256)
                          : (WqcatT + (size_t)cx * 128 * 256);
    const float* bias = isG1 ? (b0 + bx * 128) : (bqcat + cx * 128);
    const int K = 256;

    const int t = threadIdx.x;
    const int w = t >> 6, l = t & 63;
    const int bm = by * 128;
    const int wr = (w >> 1) * 64, wc = (w & 1) * 64;

    f32x4 acc[4][4] = {};

    const bf16* ag = A  + (size_t)(bm + (t >> 2)) * K + (t & 3) * 8;
    const bf16* bg = BT + (size_t)(t >> 2) * K + (t & 3) * 8;

    {
        bf16* asl = &As[0][w << 4][0];
        bf16* bsl = &Bs[0][w << 4][0];
        gload16(ag, asl);
        gload16(ag + (size_t)64 * K, (char*)asl + 4096);
        gload16(bg, bsl);
        gload16(bg + (size_t)64 * K, (char*)bsl + 4096);
    }
    __syncthreads();

    for (int tt = 0; tt < 8; ++tt) {
        const int cur = tt & 1;
        if (tt + 1 < 8) {
            const int k0 = (tt + 1) << 5;
            bf16* asl = &As[cur ^ 1][w << 4][0];
            bf16* bsl = &Bs[cur ^ 1][w << 4][0];
            gload16(ag + k0, asl);
            gload16(ag + k0 + (size_t)64 * K, (char*)asl + 4096);
            gload16(bg + k0, bsl);
            gload16(bg + k0 + (size_t)64 * K, (char*)bsl + 4096);
        }
        bf16x8 af[4], bfr[4];
        #pragma unroll
        for (int m = 0; m < 4; ++m)
            af[m] = *(const bf16x8*)&As[cur][wr + m * 16 + (l & 15)][(l >> 4) * 8];
        #pragma unroll
        for (int n2 = 0; n2 < 4; ++n2)
            bfr[n2] = *(const bf16x8*)&Bs[cur][wc + n2 * 16 + (l & 15)][(l >> 4) * 8];
        #pragma unroll
        for (int m = 0; m < 4; ++m)
            #pragma unroll
            for (int n2 = 0; n2 < 4; ++n2)
                acc[m][n2] = __builtin_amdgcn_mfma_f32_16x16x32_bf16(
                    af[m], bfr[n2], acc[m][n2], 0, 0, 0);
        __syncthreads();
    }

    #pragma unroll
    for (int m = 0; m < 4; ++m) {
        const int lrow = wr + m * 16 + ((l >> 4) << 2);
        #pragma unroll
        for (int n2 = 0; n2 < 4; ++n2) {
            const int lcol = wc + n2 * 16 + (l & 15);
            #pragma unroll
            for (int i = 0; i < 4; ++i) {
                float v = acc[m][n2][i] + bias[lcol];
                const size_t row = bm + lrow + i;
                if (isG1) {
                    H0[row * 512 + bx * 128 + lcol] = (bf16)fmaxf(v, 0.f);
                } else {
                    qcat[row * 768 + cx * 128 + lcol] = (bf16)v;
                }
            }
        }
    }
}

// ---------------------------------------------------------------------------
// Fused prep: blocks [0,4096) = features f32->bf16 (+relu copy);
//             blocks [4096,8196) = weight transposes/casts + algebra.
// WqcatT/bqcat are PRE-SCALED by 1/sqrt(32).
// ---------------------------------------------------------------------------
__global__ __launch_bounds__(256) void prep_all(
    const float* __restrict__ features,
    const float* __restrict__ W0, const float* __restrict__ W1,
    const float* __restrict__ W2, const float* __restrict__ Wq,
    const float* __restrict__ bq, const float* __restrict__ Wk,
    const float* __restrict__ Wv, const float* __restrict__ Wo,
    const float* __restrict__ bo, const float* __restrict__ bv,
    bf16* __restrict__ fbf, bf16* __restrict__ frbf,
    bf16* __restrict__ W0T, bf16* __restrict__ W1T, bf16* __restrict__ W2T,
    bf16* __restrict__ WkvT, bf16* __restrict__ WqcatT, bf16* __restrict__ WstackT,
    float* __restrict__ bqcat, float* __restrict__ biaso)
{
    if (blockIdx.x < 4096) {
        int id = blockIdx.x * 256 + threadIdx.x;
        float4 v = ((const float4*)features)[id];
        bf16x4 a, r;
        a[0] = (bf16)v.x; a[1] = (bf16)v.y; a[2] = (bf16)v.z; a[3] = (bf16)v.w;
        r[0] = (bf16)fmaxf(v.x, 0.f); r[1] = (bf16)fmaxf(v.y, 0.f);
        r[2] = (bf16)fmaxf(v.z, 0.f); r[3] = (bf16)fmaxf(v.w, 0.f);
        ((bf16x4*)fbf)[id] = a; ((bf16x4*)frbf)[id] = r;
        return;
    }
    long id = (blockIdx.x - 4096) * 256L + threadIdx.x;
    if (id < 131072) {  // W0T[n][k] = W0[k][n], 512x256
        int n = id >> 8, k = id & 255;
        W0T[id] = (bf16)W0[(long)k * 512 + n]; return;
    }
    id -= 131072;
    if (id < 262144) {  // W1T, 512x512
        int n = id >> 9, k = id & 511;
        W1T[id] = (bf16)W1[(long)k * 512 + n]; return;
    }
    id -= 262144;
    if (id < 131072) {  // W2T, 256x512
        int n = id >> 9, k = id & 511;
        W2T[id] = (bf16)W2[(long)k * 256 + n]; return;
    }
    id -= 131072;
    if (id < 131072) {  // WkvT 512x256
        int n = id >> 8, k = id & 255;
        WkvT[id] = (bf16)(n < 256 ? Wk[(long)k * 256 + n] : Wv[(long)k * 256 + (n - 256)]);
        return;
    }
    id -= 131072;
    if (id < 196608) {  // WqcatT[col][c], 768x256, scaled
        int col = id >> 8, c = id & 255;
        float s;
        if (col < 256) s = Wq[(long)c * 256 + col];
        else {
            int hd = col - 256, h = hd >> 6, d = hd & 63;
            s = 0.f;
            #pragma unroll
            for (int a = 0; a < 32; ++a)
                s += Wq[(long)c * 256 + h * 32 + a] * Wk[(long)(256 + d) * 256 + h * 32 + a];
        }
        WqcatT[id] = (bf16)(s * SCALE); return;
    }
    id -= 196608;
    if (id < 196608) {  // WstackT[col][r], 256x768
        int col = (int)(id / 768), r = (int)(id % 768);
        float s;
        if (r < 256) s = Wo[(long)r * 256 + col];
        else {
            int hd = r - 256, h = hd >> 6, d = hd & 63;
            s = 0.f;
            #pragma unroll
            for (int a = 0; a < 32; ++a)
                s += Wv[(long)(256 + d) * 256 + h * 32 + a] * Wo[(long)(h * 32 + a) * 256 + col];
        }
        WstackT[id] = (bf16)s; return;
    }
    id -= 196608;
    if (id < 768) {     // bqcat, scaled
        float s;
        if (id < 256) s = bq[id];
        else {
            int hd = (int)id - 256, h = hd >> 6, d = hd & 63;
            s = 0.f;
            #pragma unroll
            for (int a = 0; a < 32; ++a)
                s += bq[h * 32 + a] * Wk[(long)(256 + d) * 256 + h * 32 + a];
        }
        bqcat[id] = s * SCALE; return;
    }
    id -= 768;
    if (id < 256) {     // biaso = bo + bv @ Wo
        float s = bo[id];
        for (int u = 0; u < 256; ++u) s += bv[u] * Wo[(long)u * 256 + id];
        biaso[id] = s;
    }
}

// ---------------------------------------------------------------------------
// Attention (round-5 proven structure; scores pre-scaled via WqcatT fold).
// One block per node. thread = (h = t>>5, j = (t>>1)&15, part = t&1)
// ---------------------------------------------------------------------------
__global__ __launch_bounds__(256) void attn_kernel(
    const bf16* __restrict__ qcat,      // [NN, 768]  (q | qproj), pre-scaled
    const bf16* __restrict__ localKV,   // [NN, 512]  (K | V)
    const float* __restrict__ dist,     // [NN, 16, 64]
    const int*  __restrict__ structure, // [NN, 16]
    bf16* __restrict__ concat)          // [NN, 768]
{
    const int n = blockIdx.x;
    const int t = threadIdx.x;
    const int h = t >> 5, j = (t >> 1) & 15, part = t & 1;

    __shared__ float dist_s[16][65];
    __shared__ bf16  V_s[16][264];
    __shared__ float attn_s[8][16];
    __shared__ int   s_s[16];

    {
        const float* dp = dist + (long)n * (KNBR * DISTD);
        #pragma unroll
        for (int i = 0; i < 4; ++i) {
            int e = i * 256 + t;
            dist_s[e >> 6][e & 63] = dp[e];
        }
    }
    if (t < 16) s_s[t] = structure[(long)n * KNBR + t];
    __syncthreads();

    #pragma unroll
    for (int pass = 0; pass < 2; ++pass) {
        int idx = pass * 256 + t;
        int row = idx >> 5, chunk = idx & 31;
        bf16x8 v = *(const bf16x8*)(localKV + (long)s_s[row] * 512 + 256 + chunk * 8);
        *(bf16x8*)&V_s[row][chunk * 8] = v;
    }

    const bf16* qp_q = qcat + (long)n * 768 + h * 32 + part * 16;
    bf16x8 qa = *(const bf16x8*)qp_q;
    bf16x8 qb = *(const bf16x8*)(qp_q + 8);
    const bf16* qp_p = qcat + (long)n * 768 + 256 + h * 64 + part * 32;
    bf16x8 p0 = *(const bf16x8*)qp_p;
    bf16x8 p1 = *(const bf16x8*)(qp_p + 8);
    bf16x8 p2 = *(const bf16x8*)(qp_p + 16);
    bf16x8 p3 = *(const bf16x8*)(qp_p + 24);
    const bf16* kp = localKV + (long)s_s[j] * 512 + h * 32 + part * 16;
    bf16x8 ka = *(const bf16x8*)kp;
    bf16x8 kb = *(const bf16x8*)(kp + 8);

    float sc = 0.f;
    #pragma unroll
    for (int i = 0; i < 8; ++i)
        sc += (float)qa[i] * (float)ka[i] + (float)qb[i] * (float)kb[i];

    const int dbase = part * 32;
    #pragma unroll
    for (int i = 0; i < 8; ++i) sc += dist_s[j][dbase + i]      * (float)p0[i];
    #pragma unroll
    for (int i = 0; i < 8; ++i) sc += dist_s[j][dbase + 8 + i]  * (float)p1[i];
    #pragma unroll
    for (int i = 0; i < 8; ++i) sc += dist_s[j][dbase + 16 + i] * (float)p2[i];
    #pragma unroll
    for (int i = 0; i < 8; ++i) sc += dist_s[j][dbase + 24 + i] * (float)p3[i];

    sc += __shfl_xor(sc, 1);           // full (pre-scaled) score
    float m = sc;
    m = fmaxf(m, __shfl_xor(m, 2));
    m = fmaxf(m, __shfl_xor(m, 4));
    m = fmaxf(m, __shfl_xor(m, 8));
    m = fmaxf(m, __shfl_xor(m, 16));
    float e = __expf(sc - m);
    float sum = e;
    sum += __shfl_xor(sum, 2);
    sum += __shfl_xor(sum, 4);
    sum += __shfl_xor(sum, 8);
    sum += __shfl_xor(sum, 16);
    float attn = e / sum;
    if (!part) attn_s[h][j] = attn;
    __syncthreads();

    float acc = 0.f;
    #pragma unroll
    for (int j2 = 0; j2 < 16; ++j2)
        acc += attn_s[h][j2] * (float)V_s[j2][t];
    concat[(long)n * 768 + t] = (bf16)acc;

    #pragma unroll
    for (int rep = 0; rep < 2; ++rep) {
        int idx = rep * 256 + t;
        int h3 = idx >> 6, d3 = idx & 63;
        float s2 = 0.f;
        #pragma unroll
        for (int j2 = 0; j2 < 16; ++j2)
            s2 += attn_s[h3][j2] * dist_s[j2][d3];
        concat[(long)n * 768 + 256 + idx] = (bf16)s2;
    }
}

// ---------------------------------------------------------------------------
extern "C" void kernel_launch(void* const* d_in, const int* in_sizes, int n_in,
                              void* d_out, int out_size, void* d_ws, size_t ws_size,
                              hipStream_t stream)
{
    const float* features = (const float*)d_in[0];
    const float* dist     = (const float*)d_in[1];
    const int*   structure= (const int*)d_in[2];
    const float* W0 = (const float*)d_in[3];
    const float* b0 = (const float*)d_in[4];
    const float* W1 = (const float*)d_in[5];
    const float* b1 = (const float*)d_in[6];
    const float* W2 = (const float*)d_in[7];
    const float* b2 = (const float*)d_in[8];
    const float* Wq = (const float*)d_in[9];
    const float* bq = (const float*)d_in[10];
    const float* Wk = (const float*)d_in[11];
    // d_in[12] = bk : dropped exactly (softmax-invariant per-head shift)
    const float* Wv = (const float*)d_in[13];
    const float* bv = (const float*)d_in[14];
    const float* Wo = (const float*)d_in[15];
    const float* bo = (const float*)d_in[16];
    float* out = (float*)d_out;

    const size_t MB = 1u << 20;
    char* w = (char*)d_ws;
    // live intervals:
    bf16*  fbf     = (bf16*)(w + 0 * MB);    // [0,8)    prep -> g1qcat
    bf16*  local_b = (bf16*)(w + 0 * MB);    // [0,8)    G3 -> KV     (fbf dead)
    bf16*  frbf    = (bf16*)(w + 8 * MB);    // [8,16)   prep -> g1qcat
    bf16*  localKV = (bf16*)(w + 8 * MB);    // [8,24)   KV -> attn   (frbf/H0 dead)
    bf16*  H0      = (bf16*)(w + 16 * MB);   // [16,32)  g1qcat -> G2
    bf16*  qcat    = (bf16*)(w + 32 * MB);   // [32,56)  g1qcat -> attn
    bf16*  H1      = (bf16*)(w + 56 * MB);   // [56,72)  G2 -> G3
    bf16*  concat  = (bf16*)(w + 56 * MB);   // [56,80)  attn -> final (H1 dead)
    char*  wb      = w + 80 * MB;            // weights: prep -> final
    bf16*  W0T     = (bf16*)(wb + 0);
    bf16*  W1T     = (bf16*)(wb + 262144);
    bf16*  W2T     = (bf16*)(wb + 786432);
    bf16*  WkvT    = (bf16*)(wb + 1048576);
    bf16*  WqcatT  = (bf16*)(wb + 1310720);
    bf16*  WstackT = (bf16*)(wb + 1703936);
    float* bqcat   = (float*)(wb + 2097152);
    float* biaso   = (float*)(wb + 2100224);

    dim3 blk(256);

    prep_all<<<dim3(8196), blk, 0, stream>>>(
        features, W0, W1, W2, Wq, bq, Wk, Wv, Wo, bo, bv,
        fbf, frbf, W0T, W1T, W2T, WkvT, WqcatT, WstackT, bqcat, biaso);

    // fused: H0 = relu(relu(f)@W0+b0); qcat = f@Wqcat+bqcat (pre-scaled)
    g1qcat_kernel<<<dim3(10, 128), blk, 0, stream>>>(
        fbf, frbf, W0T, b0, WqcatT, bqcat, H0, qcat);

    // W1: H1 = relu(H0@W1+b1)             (TN=64 -> 1024 blocks, 4/CU)
    gemm128<true,  true,  false, bf16, 64><<<dim3(8, 128), blk, 0, stream>>>(
        H0, W1T, b1, nullptr, H1, NN, 512, 512);
    // W2: local = relu(H1@W2+b2)          (TN=64 -> 512 blocks, 2/CU)
    gemm128<true,  true,  false, bf16, 64><<<dim3(4, 128), blk, 0, stream>>>(
        H1, W2T, b2, nullptr, local_b, NN, 256, 512);
    // KV: localKV = local @ [Wk|Wv]       (TN=64 -> 1024 blocks, 4/CU)
    gemm128<false, false, false, bf16, 64><<<dim3(8, 128), blk, 0, stream>>>(
        local_b, WkvT, nullptr, nullptr, localKV, NN, 512, 256);

    attn_kernel<<<dim3(NN), blk, 0, stream>>>(
        qcat, localKV, dist, structure, concat);

    // out = concat @ [Wo ; U] + (bo + bv@Wo) + features   (TN=64, 512 blocks)
    gemm128<true,  false, true,  float, 64><<<dim3(4, 128), blk, 0, stream>>>(
        concat, WstackT, biaso, features, out, NN, 256, 768);
}

// Round 8
// 162.110 us; speedup vs baseline: 1.1104x; 1.0986x over previous
//
#include <hip/hip_runtime.h>
#include <hip/hip_bf16.h>

#define NN 16384
#define SIZE 256
#define DISTD 64
#define KNBR 16
#define HEADS 8
#define HIDDEN 512
#define HA 256
#define SCALE 0.17677669529663687f

typedef __bf16 bf16;
typedef bf16 bf16x2 __attribute__((ext_vector_type(2)));
typedef bf16 bf16x4 __attribute__((ext_vector_type(4)));
typedef bf16 bf16x8 __attribute__((ext_vector_type(8)));
typedef float f32x4 __attribute__((ext_vector_type(4)));

__device__ __forceinline__ void gload16(const void* g, void* l) {
    __builtin_amdgcn_global_load_lds(
        (const __attribute__((address_space(1))) unsigned int*)g,
        (__attribute__((address_space(3))) unsigned int*)l, 16, 0, 0);
}

// ---------------------------------------------------------------------------
// 2-phase double-buffered 128x128 GEMM, BK = 32*SUBS.
// SUBS=2: each K-step stages/computes two proven BK=32 sub-panels with ONE
// barrier -> halves barrier-drain count per K. 64KB LDS = 2 blocks/CU, which
// equals what the 256-512-block grids give anyway (no occupancy loss).
// ---------------------------------------------------------------------------
template<bool BIAS, bool RELU_OUT, bool RESID, typename OutT, int SUBS>
__global__ __launch_bounds__(256) void gemm128(
    const bf16* __restrict__ A, const bf16* __restrict__ BT,
    const float* __restrict__ bias, const float* __restrict__ resid,
    OutT* __restrict__ C, int M, int N, int K)
{
    __shared__ alignas(16) bf16 As[2][SUBS][128][32];
    __shared__ alignas(16) bf16 Bs[2][SUBS][128][32];

    const int t = threadIdx.x;
    const int w = t >> 6, l = t & 63;
    const int bm = blockIdx.y * 128, bn = blockIdx.x * 128;
    const int wr = (w >> 1) * 64, wc = (w & 1) * 64;
    const int BK = 32 * SUBS;

    f32x4 acc[4][4] = {};

    const bf16* ag = A  + (size_t)(bm + (t >> 2)) * K + (t & 3) * 8;
    const bf16* bg = BT + (size_t)(bn + (t >> 2)) * K + (t & 3) * 8;

    auto STAGE = [&](int buf, int k0) {
        #pragma unroll
        for (int s = 0; s < SUBS; ++s) {
            bf16* asl = &As[buf][s][w << 4][0];
            bf16* bsl = &Bs[buf][s][w << 4][0];
            gload16(ag + k0 + s * 32, asl);
            gload16(ag + k0 + s * 32 + (size_t)64 * K, (char*)asl + 4096);
            gload16(bg + k0 + s * 32, bsl);
            gload16(bg + k0 + s * 32 + (size_t)64 * K, (char*)bsl + 4096);
        }
    };

    const int nt = K / BK;
    STAGE(0, 0);
    __syncthreads();

    for (int tt = 0; tt < nt; ++tt) {
        const int cur = tt & 1;
        if (tt + 1 < nt) STAGE(cur ^ 1, (tt + 1) * BK);

        #pragma unroll
        for (int s = 0; s < SUBS; ++s) {
            bf16x8 af[4], bfr[4];
            #pragma unroll
            for (int m = 0; m < 4; ++m)
                af[m] = *(const bf16x8*)&As[cur][s][wr + m * 16 + (l & 15)][(l >> 4) * 8];
            #pragma unroll
            for (int n2 = 0; n2 < 4; ++n2)
                bfr[n2] = *(const bf16x8*)&Bs[cur][s][wc + n2 * 16 + (l & 15)][(l >> 4) * 8];
            #pragma unroll
            for (int m = 0; m < 4; ++m)
                #pragma unroll
                for (int n2 = 0; n2 < 4; ++n2)
                    acc[m][n2] = __builtin_amdgcn_mfma_f32_16x16x32_bf16(
                        af[m], bfr[n2], acc[m][n2], 0, 0, 0);
        }
        __syncthreads();
    }

    #pragma unroll
    for (int m = 0; m < 4; ++m) {
        const int row = bm + wr + m * 16 + ((l >> 4) << 2);
        #pragma unroll
        for (int n2 = 0; n2 < 4; ++n2) {
            const int col = bn + wc + n2 * 16 + (l & 15);
            #pragma unroll
            for (int i = 0; i < 4; ++i) {
                float v = acc[m][n2][i];
                if (BIAS) v += bias[col];
                if (RESID) v += resid[(size_t)(row + i) * N + col];
                if (RELU_OUT) v = fmaxf(v, 0.f);
                C[(size_t)(row + i) * N + col] = (OutT)v;
            }
        }
    }
}

// ---------------------------------------------------------------------------
// Fused G1 + qcat dispatch (both K=256), BK=32 (keeps 5 blocks/CU). grid (10,128):
//  bx<4 : H0   = relu(frbf @ W0T + b0)            (bf16, ld 512)
//  bx>=4: qcat = fbf @ Wqcat_cols + bqcat          (bf16, ld 768, pre-scaled)
// ---------------------------------------------------------------------------
__global__ __launch_bounds__(256) void g1qcat_kernel(
    const bf16* __restrict__ fbf, const bf16* __restrict__ frbf,
    const bf16* __restrict__ W0T, const float* __restrict__ b0,
    const bf16* __restrict__ WqcatT, const float* __restrict__ bqcat,
    bf16* __restrict__ H0, bf16* __restrict__ qcat)
{
    __shared__ alignas(16) bf16 As[2][128][32];
    __shared__ alignas(16) bf16 Bs[2][128][32];

    const int bx = blockIdx.x, by = blockIdx.y;
    const bool isG1 = bx < 4;
    const int cx = bx - 4;
    const bf16* A  = isG1 ? frbf : fbf;
    const bf16* BT = isG1 ? (W0T + (size_t)bx * 128 * 256)
                          : (WqcatT + (size_t)cx * 128 * 256);
    const float* bias = isG1 ? (b0 + bx * 128) : (bqcat + cx * 128);
    const int K = 256;

    const int t = threadIdx.x;
    const int w = t >> 6, l = t & 63;
    const int bm = by * 128;
    const int wr = (w >> 1) * 64, wc = (w & 1) * 64;

    f32x4 acc[4][4] = {};

    const bf16* ag = A  + (size_t)(bm + (t >> 2)) * K + (t & 3) * 8;
    const bf16* bg = BT + (size_t)(t >> 2) * K + (t & 3) * 8;

    {
        bf16* asl = &As[0][w << 4][0];
        bf16* bsl = &Bs[0][w << 4][0];
        gload16(ag, asl);
        gload16(ag + (size_t)64 * K, (char*)asl + 4096);
        gload16(bg, bsl);
        gload16(bg + (size_t)64 * K, (char*)bsl + 4096);
    }
    __syncthreads();

    for (int tt = 0; tt < 8; ++tt) {
        const int cur = tt & 1;
        if (tt + 1 < 8) {
            const int k0 = (tt + 1) << 5;
            bf16* asl = &As[cur ^ 1][w << 4][0];
            bf16* bsl = &Bs[cur ^ 1][w << 4][0];
            gload16(ag + k0, asl);
            gload16(ag + k0 + (size_t)64 * K, (char*)asl + 4096);
            gload16(bg + k0, bsl);
            gload16(bg + k0 + (size_t)64 * K, (char*)bsl + 4096);
        }
        bf16x8 af[4], bfr[4];
        #pragma unroll
        for (int m = 0; m < 4; ++m)
            af[m] = *(const bf16x8*)&As[cur][wr + m * 16 + (l & 15)][(l >> 4) * 8];
        #pragma unroll
        for (int n2 = 0; n2 < 4; ++n2)
            bfr[n2] = *(const bf16x8*)&Bs[cur][wc + n2 * 16 + (l & 15)][(l >> 4) * 8];
        #pragma unroll
        for (int m = 0; m < 4; ++m)
            #pragma unroll
            for (int n2 = 0; n2 < 4; ++n2)
                acc[m][n2] = __builtin_amdgcn_mfma_f32_16x16x32_bf16(
                    af[m], bfr[n2], acc[m][n2], 0, 0, 0);
        __syncthreads();
    }

    #pragma unroll
    for (int m = 0; m < 4; ++m) {
        const int lrow = wr + m * 16 + ((l >> 4) << 2);
        #pragma unroll
        for (int n2 = 0; n2 < 4; ++n2) {
            const int lcol = wc + n2 * 16 + (l & 15);
            #pragma unroll
            for (int i = 0; i < 4; ++i) {
                float v = acc[m][n2][i] + bias[lcol];
                const size_t row = bm + lrow + i;
                if (isG1) {
                    H0[row * 512 + bx * 128 + lcol] = (bf16)fmaxf(v, 0.f);
                } else {
                    qcat[row * 768 + cx * 128 + lcol] = (bf16)v;
                }
            }
        }
    }
}

// ---------------------------------------------------------------------------
// Fused prep: blocks [0,4096) = features f32->bf16 (+relu copy);
//             blocks [4096,8196) = weight transposes/casts + algebra.
// WqcatT/bqcat are PRE-SCALED by 1/sqrt(32).
// ---------------------------------------------------------------------------
__global__ __launch_bounds__(256) void prep_all(
    const float* __restrict__ features,
    const float* __restrict__ W0, const float* __restrict__ W1,
    const float* __restrict__ W2, const float* __restrict__ Wq,
    const float* __restrict__ bq, const float* __restrict__ Wk,
    const float* __restrict__ Wv, const float* __restrict__ Wo,
    const float* __restrict__ bo, const float* __restrict__ bv,
    bf16* __restrict__ fbf, bf16* __restrict__ frbf,
    bf16* __restrict__ W0T, bf16* __restrict__ W1T, bf16* __restrict__ W2T,
    bf16* __restrict__ WkvT, bf16* __restrict__ WqcatT, bf16* __restrict__ WstackT,
    float* __restrict__ bqcat, float* __restrict__ biaso)
{
    if (blockIdx.x < 4096) {
        int id = blockIdx.x * 256 + threadIdx.x;
        float4 v = ((const float4*)features)[id];
        bf16x4 a, r;
        a[0] = (bf16)v.x; a[1] = (bf16)v.y; a[2] = (bf16)v.z; a[3] = (bf16)v.w;
        r[0] = (bf16)fmaxf(v.x, 0.f); r[1] = (bf16)fmaxf(v.y, 0.f);
        r[2] = (bf16)fmaxf(v.z, 0.f); r[3] = (bf16)fmaxf(v.w, 0.f);
        ((bf16x4*)fbf)[id] = a; ((bf16x4*)frbf)[id] = r;
        return;
    }
    long id = (blockIdx.x - 4096) * 256L + threadIdx.x;
    if (id < 131072) {  // W0T[n][k] = W0[k][n], 512x256
        int n = id >> 8, k = id & 255;
        W0T[id] = (bf16)W0[(long)k * 512 + n]; return;
    }
    id -= 131072;
    if (id < 262144) {  // W1T, 512x512
        int n = id >> 9, k = id & 511;
        W1T[id] = (bf16)W1[(long)k * 512 + n]; return;
    }
    id -= 262144;
    if (id < 131072) {  // W2T, 256x512
        int n = id >> 9, k = id & 511;
        W2T[id] = (bf16)W2[(long)k * 256 + n]; return;
    }
    id -= 131072;
    if (id < 131072) {  // WkvT 512x256
        int n = id >> 8, k = id & 255;
        WkvT[id] = (bf16)(n < 256 ? Wk[(long)k * 256 + n] : Wv[(long)k * 256 + (n - 256)]);
        return;
    }
    id -= 131072;
    if (id < 196608) {  // WqcatT[col][c], 768x256, scaled
        int col = id >> 8, c = id & 255;
        float s;
        if (col < 256) s = Wq[(long)c * 256 + col];
        else {
            int hd = col - 256, h = hd >> 6, d = hd & 63;
            s = 0.f;
            #pragma unroll
            for (int a = 0; a < 32; ++a)
                s += Wq[(long)c * 256 + h * 32 + a] * Wk[(long)(256 + d) * 256 + h * 32 + a];
        }
        WqcatT[id] = (bf16)(s * SCALE); return;
    }
    id -= 196608;
    if (id < 196608) {  // WstackT[col][r], 256x768
        int col = (int)(id / 768), r = (int)(id % 768);
        float s;
        if (r < 256) s = Wo[(long)r * 256 + col];
        else {
            int hd = r - 256, h = hd >> 6, d = hd & 63;
            s = 0.f;
            #pragma unroll
            for (int a = 0; a < 32; ++a)
                s += Wv[(long)(256 + d) * 256 + h * 32 + a] * Wo[(long)(h * 32 + a) * 256 + col];
        }
        WstackT[id] = (bf16)s; return;
    }
    id -= 196608;
    if (id < 768) {     // bqcat, scaled
        float s;
        if (id < 256) s = bq[id];
        else {
            int hd = (int)id - 256, h = hd >> 6, d = hd & 63;
            s = 0.f;
            #pragma unroll
            for (int a = 0; a < 32; ++a)
                s += bq[h * 32 + a] * Wk[(long)(256 + d) * 256 + h * 32 + a];
        }
        bqcat[id] = s * SCALE; return;
    }
    id -= 768;
    if (id < 256) {     // biaso = bo + bv @ Wo
        float s = bo[id];
        for (int u = 0; u < 256; ++u) s += bv[u] * Wo[(long)u * 256 + id];
        biaso[id] = s;
    }
}

// ---------------------------------------------------------------------------
// Attention: round-5 proven score/softmax path (bf16 qcat, pre-scaled) +
// round-6 proven widened phase C (bf16x2 o-pairs, float4 wd, stride-68 dist).
// ---------------------------------------------------------------------------
__global__ __launch_bounds__(256) void attn_kernel(
    const bf16* __restrict__ qcat,      // [NN, 768]  (q | qproj), pre-scaled
    const bf16* __restrict__ localKV,   // [NN, 512]  (K | V)
    const float* __restrict__ dist,     // [NN, 16, 64]
    const int*  __restrict__ structure, // [NN, 16]
    bf16* __restrict__ concat)          // [NN, 768]
{
    const int n = blockIdx.x;
    const int t = threadIdx.x;
    const int h = t >> 5, j = (t >> 1) & 15, part = t & 1;

    __shared__ float dist_s[16][68];   // 272B rows: 16B-aligned for float4 reads
    __shared__ bf16  V_s[16][264];
    __shared__ float attn_s[8][16];
    __shared__ int   s_s[16];

    {
        const float* dp = dist + (long)n * (KNBR * DISTD);
        #pragma unroll
        for (int i = 0; i < 4; ++i) {
            int e = i * 256 + t;
            dist_s[e >> 6][e & 63] = dp[e];
        }
    }
    if (t < 16) s_s[t] = structure[(long)n * KNBR + t];
    __syncthreads();

    #pragma unroll
    for (int pass = 0; pass < 2; ++pass) {
        int idx = pass * 256 + t;
        int row = idx >> 5, chunk = idx & 31;
        bf16x8 v = *(const bf16x8*)(localKV + (long)s_s[row] * 512 + 256 + chunk * 8);
        *(bf16x8*)&V_s[row][chunk * 8] = v;
    }

    const bf16* qp_q = qcat + (long)n * 768 + h * 32 + part * 16;
    bf16x8 qa = *(const bf16x8*)qp_q;
    bf16x8 qb = *(const bf16x8*)(qp_q + 8);
    const bf16* qp_p = qcat + (long)n * 768 + 256 + h * 64 + part * 32;
    bf16x8 p0 = *(const bf16x8*)qp_p;
    bf16x8 p1 = *(const bf16x8*)(qp_p + 8);
    bf16x8 p2 = *(const bf16x8*)(qp_p + 16);
    bf16x8 p3 = *(const bf16x8*)(qp_p + 24);
    const bf16* kp = localKV + (long)s_s[j] * 512 + h * 32 + part * 16;
    bf16x8 ka = *(const bf16x8*)kp;
    bf16x8 kb = *(const bf16x8*)(kp + 8);

    float sc = 0.f;
    #pragma unroll
    for (int i = 0; i < 8; ++i)
        sc += (float)qa[i] * (float)ka[i] + (float)qb[i] * (float)kb[i];

    const int dbase = part * 32;
    #pragma unroll
    for (int i = 0; i < 8; ++i) sc += dist_s[j][dbase + i]      * (float)p0[i];
    #pragma unroll
    for (int i = 0; i < 8; ++i) sc += dist_s[j][dbase + 8 + i]  * (float)p1[i];
    #pragma unroll
    for (int i = 0; i < 8; ++i) sc += dist_s[j][dbase + 16 + i] * (float)p2[i];
    #pragma unroll
    for (int i = 0; i < 8; ++i) sc += dist_s[j][dbase + 24 + i] * (float)p3[i];

    sc += __shfl_xor(sc, 1);           // full (pre-scaled) score
    float m = sc;
    m = fmaxf(m, __shfl_xor(m, 2));
    m = fmaxf(m, __shfl_xor(m, 4));
    m = fmaxf(m, __shfl_xor(m, 8));
    m = fmaxf(m, __shfl_xor(m, 16));
    float e = __expf(sc - m);
    float sum = e;
    sum += __shfl_xor(sum, 2);
    sum += __shfl_xor(sum, 4);
    sum += __shfl_xor(sum, 8);
    sum += __shfl_xor(sum, 16);
    float attn = e / sum;
    if (!part) attn_s[h][j] = attn;
    __syncthreads();

    if (t < 128) {
        // o: col pair (2t, 2t+1)
        const int c0 = t * 2;
        const int hh = t >> 4;
        float a0 = 0.f, a1 = 0.f;
        #pragma unroll
        for (int j2 = 0; j2 < 16; ++j2) {
            float wgt = attn_s[hh][j2];
            bf16x2 pv = *(const bf16x2*)&V_s[j2][c0];
            a0 += wgt * (float)pv[0];
            a1 += wgt * (float)pv[1];
        }
        bf16x2 o2; o2[0] = (bf16)a0; o2[1] = (bf16)a1;
        *(bf16x2*)&concat[(long)n * 768 + c0] = o2;
    } else {
        // wd: 4 outputs (u*4 .. u*4+3)
        const int u = t - 128;
        const int base = u * 4;
        const int h3 = u >> 4, d3 = (u & 15) * 4;
        f32x4 acc4 = {};
        #pragma unroll
        for (int j2 = 0; j2 < 16; ++j2) {
            float wgt = attn_s[h3][j2];
            const f32x4 dv = *(const f32x4*)&dist_s[j2][d3];
            acc4 += wgt * dv;
        }
        bf16x4 o4;
        #pragma unroll
        for (int i = 0; i < 4; ++i) o4[i] = (bf16)acc4[i];
        *(bf16x4*)&concat[(long)n * 768 + 256 + base] = o4;
    }
}

// ---------------------------------------------------------------------------
extern "C" void kernel_launch(void* const* d_in, const int* in_sizes, int n_in,
                              void* d_out, int out_size, void* d_ws, size_t ws_size,
                              hipStream_t stream)
{
    const float* features = (const float*)d_in[0];
    const float* dist     = (const float*)d_in[1];
    const int*   structure= (const int*)d_in[2];
    const float* W0 = (const float*)d_in[3];
    const float* b0 = (const float*)d_in[4];
    const float* W1 = (const float*)d_in[5];
    const float* b1 = (const float*)d_in[6];
    const float* W2 = (const float*)d_in[7];
    const float* b2 = (const float*)d_in[8];
    const float* Wq = (const float*)d_in[9];
    const float* bq = (const float*)d_in[10];
    const float* Wk = (const float*)d_in[11];
    // d_in[12] = bk : dropped exactly (softmax-invariant per-head shift)
    const float* Wv = (const float*)d_in[13];
    const float* bv = (const float*)d_in[14];
    const float* Wo = (const float*)d_in[15];
    const float* bo = (const float*)d_in[16];
    float* out = (float*)d_out;

    const size_t MB = 1u << 20;
    char* w = (char*)d_ws;
    // live intervals:
    bf16*  fbf     = (bf16*)(w + 0 * MB);    // [0,8)    prep -> g1qcat
    bf16*  local_b = (bf16*)(w + 0 * MB);    // [0,8)    G3 -> KV     (fbf dead)
    bf16*  frbf    = (bf16*)(w + 8 * MB);    // [8,16)   prep -> g1qcat
    bf16*  localKV = (bf16*)(w + 8 * MB);    // [8,24)   KV -> attn   (frbf/H0 dead)
    bf16*  H0      = (bf16*)(w + 16 * MB);   // [16,32)  g1qcat -> G2
    bf16*  qcat    = (bf16*)(w + 32 * MB);   // [32,56)  g1qcat -> attn
    bf16*  H1      = (bf16*)(w + 56 * MB);   // [56,72)  G2 -> G3
    bf16*  concat  = (bf16*)(w + 56 * MB);   // [56,80)  attn -> final (H1 dead)
    char*  wb      = w + 80 * MB;            // weights: prep -> final
    bf16*  W0T     = (bf16*)(wb + 0);
    bf16*  W1T     = (bf16*)(wb + 262144);
    bf16*  W2T     = (bf16*)(wb + 786432);
    bf16*  WkvT    = (bf16*)(wb + 1048576);
    bf16*  WqcatT  = (bf16*)(wb + 1310720);
    bf16*  WstackT = (bf16*)(wb + 1703936);
    float* bqcat   = (float*)(wb + 2097152);
    float* biaso   = (float*)(wb + 2100224);

    dim3 blk(256);

    prep_all<<<dim3(8196), blk, 0, stream>>>(
        features, W0, W1, W2, Wq, bq, Wk, Wv, Wo, bo, bv,
        fbf, frbf, W0T, W1T, W2T, WkvT, WqcatT, WstackT, bqcat, biaso);

    // fused: H0 = relu(relu(f)@W0+b0); qcat = f@Wqcat+bqcat (pre-scaled)
    g1qcat_kernel<<<dim3(10, 128), blk, 0, stream>>>(
        fbf, frbf, W0T, b0, WqcatT, bqcat, H0, qcat);

    // W1: H1 = relu(H0@W1+b1)          (TN=128, BK=64: 512 blocks, 2/CU)
    gemm128<true,  true,  false, bf16, 2><<<dim3(4, 128), blk, 0, stream>>>(
        H0, W1T, b1, nullptr, H1, NN, 512, 512);
    // W2: local = relu(H1@W2+b2)       (256 blocks)
    gemm128<true,  true,  false, bf16, 2><<<dim3(2, 128), blk, 0, stream>>>(
        H1, W2T, b2, nullptr, local_b, NN, 256, 512);
    // KV: localKV = local @ [Wk|Wv]    (512 blocks)
    gemm128<false, false, false, bf16, 2><<<dim3(4, 128), blk, 0, stream>>>(
        local_b, WkvT, nullptr, nullptr, localKV, NN, 512, 256);

    attn_kernel<<<dim3(NN), blk, 0, stream>>>(
        qcat, localKV, dist, structure, concat);

    // out = concat @ [Wo ; U] + (bo + bv@Wo) + features  (256 blocks)
    gemm128<true,  false, true,  float, 2><<<dim3(2, 128), blk, 0, stream>>>(
        concat, WstackT, biaso, features, out, NN, 256, 768);
}